// Round 2
// baseline (28133.011 us; speedup 1.0000x reference)
//
#include <hip/hip_runtime.h>
#include <cstdint>
#include <cstddef>

#define D        512
#define NROWS    16384
#define NCODES   8192
#define BMM      128   // rows per block tile
#define BNN      128   // codes per block tile
#define BKK      16    // k chunk
#define NKC      (D / BKK)
#define COLBLKS  (NCODES / BNN)   // 64
#define ROWBLKS  (NROWS / BMM)    // 128

// ---------------------------------------------------------------------------
// Kernel 1: e2[c] = sum_d embed[c][d]^2.  One wave per code row.
// ---------------------------------------------------------------------------
__global__ void vq_e2_kernel(const float* __restrict__ embed,
                             float* __restrict__ e2) {
  const int w    = (blockIdx.x * blockDim.x + threadIdx.x) >> 6;
  const int lane = threadIdx.x & 63;
  const float* p = embed + (size_t)w * D + lane * 8;
  const float4 a = *(const float4*)p;
  const float4 b = *(const float4*)(p + 4);
  float s = a.x * a.x + a.y * a.y + a.z * a.z + a.w * a.w +
            b.x * b.x + b.y * b.y + b.z * b.z + b.w * b.w;
#pragma unroll
  for (int m = 32; m >= 1; m >>= 1) s += __shfl_xor(s, m, 64);
  if (lane == 0) e2[w] = s;
}

// order-preserving fp32 -> u32 key (ascending float -> ascending uint)
__device__ __forceinline__ unsigned int fkey(float f) {
  unsigned int u = __float_as_uint(f);
  return (u & 0x80000000u) ? ~u : (u | 0x80000000u);
}

// ---------------------------------------------------------------------------
// Kernel 2: streamed fp32 GEMM tile (128x128, BK=16 double-buffered) computing
// dot(x_row, e_code); fused per-tile argmin of score = e2[c] - 2*dot,
// merged globally via atomicMin on packed (key<<32 | idx).
//   256 threads (4 waves). Thread (tr=tid>>4, tc=tid&15) owns an 8x8 tile.
//   LDS: 2*2*16*132*4 = 33.8 KB -> 4 blocks/CU.
// ---------------------------------------------------------------------------
__global__ __launch_bounds__(256, 4) void vq_gemm_kernel(
    const float* __restrict__ x, const float* __restrict__ embed,
    const float* __restrict__ e2g, unsigned long long* __restrict__ wsmin) {
  __shared__ float as[2][BKK][BMM + 4];   // k-major, stride 132
  __shared__ float bs[2][BKK][BNN + 4];

  const int tid    = threadIdx.x;
  const int colBlk = blockIdx.x & (COLBLKS - 1);
  const int rowBlk = blockIdx.x >> 6;
  const int row0   = rowBlk * BMM;
  const int c0     = colBlk * BNN;
  const int tr     = tid >> 4;   // 0..15 (row group)
  const int tc     = tid & 15;   // 0..15 (col group)

  // staging: float4 f = 2*tid + l; m = f>>2 (0..127), kq = (f&3)*4
  float4 ra[2], rb[2];
  const int sm0 = (tid * 2) >> 2;          // row/code index for l=0
  const int sq0 = ((tid * 2) & 3) * 4;     // k offset for l=0
  const int sm1 = (tid * 2 + 1) >> 2;
  const int sq1 = ((tid * 2 + 1) & 3) * 4;

#define GLOB_LOAD(kc)                                                        \
  do {                                                                       \
    const int kb = (kc) * BKK;                                               \
    ra[0] = *(const float4*)(x + (size_t)(row0 + sm0) * D + kb + sq0);       \
    ra[1] = *(const float4*)(x + (size_t)(row0 + sm1) * D + kb + sq1);       \
    rb[0] = *(const float4*)(embed + (size_t)(c0 + sm0) * D + kb + sq0);     \
    rb[1] = *(const float4*)(embed + (size_t)(c0 + sm1) * D + kb + sq1);     \
  } while (0)

#define LDS_WRITE(buf)                                                       \
  do {                                                                       \
    as[buf][sq0 + 0][sm0] = ra[0].x; as[buf][sq0 + 1][sm0] = ra[0].y;        \
    as[buf][sq0 + 2][sm0] = ra[0].z; as[buf][sq0 + 3][sm0] = ra[0].w;        \
    as[buf][sq1 + 0][sm1] = ra[1].x; as[buf][sq1 + 1][sm1] = ra[1].y;        \
    as[buf][sq1 + 2][sm1] = ra[1].z; as[buf][sq1 + 3][sm1] = ra[1].w;        \
    bs[buf][sq0 + 0][sm0] = rb[0].x; bs[buf][sq0 + 1][sm0] = rb[0].y;        \
    bs[buf][sq0 + 2][sm0] = rb[0].z; bs[buf][sq0 + 3][sm0] = rb[0].w;        \
    bs[buf][sq1 + 0][sm1] = rb[1].x; bs[buf][sq1 + 1][sm1] = rb[1].y;        \
    bs[buf][sq1 + 2][sm1] = rb[1].z; bs[buf][sq1 + 3][sm1] = rb[1].w;        \
  } while (0)

  float acc[8][8];
#pragma unroll
  for (int i = 0; i < 8; ++i)
#pragma unroll
    for (int j = 0; j < 8; ++j) acc[i][j] = 0.f;

  GLOB_LOAD(0);
  LDS_WRITE(0);
  __syncthreads();

  int cur = 0;
  for (int kc = 0; kc < NKC; ++kc) {
    if (kc + 1 < NKC) GLOB_LOAD(kc + 1);   // vmem in flight over compute
#pragma unroll
    for (int k = 0; k < BKK; ++k) {
      float a[8], b[8];
      *(float4*)&a[0] = *(const float4*)&as[cur][k][tr * 8];
      *(float4*)&a[4] = *(const float4*)&as[cur][k][tr * 8 + 4];
      *(float4*)&b[0] = *(const float4*)&bs[cur][k][tc * 8];
      *(float4*)&b[4] = *(const float4*)&bs[cur][k][tc * 8 + 4];
#pragma unroll
      for (int i = 0; i < 8; ++i)
#pragma unroll
        for (int j = 0; j < 8; ++j) acc[i][j] = fmaf(a[i], b[j], acc[i][j]);
    }
    if (kc + 1 < NKC) {
      LDS_WRITE(cur ^ 1);   // other buffer: free since barrier of kc-1
      __syncthreads();
    }
    cur ^= 1;
  }

  // epilogue: score = e2 - 2*dot ; per-row argmin over this 128-code tile
  float e2a[8];
  *(float4*)&e2a[0] = *(const float4*)(e2g + c0 + tc * 8);
  *(float4*)&e2a[4] = *(const float4*)(e2g + c0 + tc * 8 + 4);
#pragma unroll
  for (int i = 0; i < 8; ++i) {
    float bv = 3.4e38f;
    int   bi = 0;
#pragma unroll
    for (int j = 0; j < 8; ++j) {
      const float s = fmaf(-2.f, acc[i][j], e2a[j]);
      if (s < bv) { bv = s; bi = c0 + tc * 8 + j; }   // strict <: lowest idx
    }
    // reduce across the 16 tc-lanes (same tr) — contiguous 16-lane group
#pragma unroll
    for (int m = 8; m >= 1; m >>= 1) {
      const float ov = __shfl_xor(bv, m, 64);
      const int   oi = __shfl_xor(bi, m, 64);
      if (ov < bv || (ov == bv && oi < bi)) { bv = ov; bi = oi; }
    }
    if (tc == 0) {
      const unsigned long long packed =
          ((unsigned long long)fkey(bv) << 32) | (unsigned int)bi;
      atomicMin(&wsmin[row0 + tr * 8 + i], packed);
    }
  }
#undef GLOB_LOAD
#undef LDS_WRITE
}

// ---------------------------------------------------------------------------
// Kernel 3: gather winning rows, write q, idx (as float), commit loss.
// One wave per row.
// ---------------------------------------------------------------------------
__global__ void vq_finish_kernel(const float* __restrict__ x,
                                 const float* __restrict__ embed,
                                 const unsigned long long* __restrict__ wsmin,
                                 float* __restrict__ out_q,
                                 float* __restrict__ out_idx,
                                 float* __restrict__ out_loss) {
  const int row  = blockIdx.x * 4 + (threadIdx.x >> 6);
  const int lane = threadIdx.x & 63;
  const int idx  = (int)(wsmin[row] & 0xFFFFFFFFull);
  if (lane == 0) out_idx[row] = (float)idx;

  const float* ep = embed + (size_t)idx * D + lane * 8;
  const float* xp = x + (size_t)row * D + lane * 8;
  float* qp       = out_q + (size_t)row * D + lane * 8;

  const float4 e0 = *(const float4*)ep;
  const float4 e1 = *(const float4*)(ep + 4);
  const float4 x0 = *(const float4*)xp;
  const float4 x1 = *(const float4*)(xp + 4);
  *(float4*)qp       = e0;   // x + sg(q - x) == q numerically
  *(float4*)(qp + 4) = e1;

  float l = (e0.x - x0.x) * (e0.x - x0.x) + (e0.y - x0.y) * (e0.y - x0.y) +
            (e0.z - x0.z) * (e0.z - x0.z) + (e0.w - x0.w) * (e0.w - x0.w) +
            (e1.x - x1.x) * (e1.x - x1.x) + (e1.y - x1.y) * (e1.y - x1.y) +
            (e1.z - x1.z) * (e1.z - x1.z) + (e1.w - x1.w) * (e1.w - x1.w);
#pragma unroll
  for (int m = 32; m >= 1; m >>= 1) l += __shfl_xor(l, m, 64);
  if (lane == 0)
    atomicAdd(out_loss, l * (1.f / (float)((size_t)NROWS * D)));
}

// ---------------------------------------------------------------------------
extern "C" void kernel_launch(void* const* d_in, const int* in_sizes, int n_in,
                              void* d_out, int out_size, void* d_ws,
                              size_t ws_size, hipStream_t stream) {
  (void)in_sizes; (void)n_in; (void)out_size; (void)ws_size;
  const float* x     = (const float*)d_in[0];
  const float* embed = (const float*)d_in[1];

  unsigned long long* wsmin = (unsigned long long*)d_ws;       // 16384 * 8 B
  float* e2 = (float*)((char*)d_ws + (size_t)NROWS * 8);       // 8192 * 4 B

  float* out_q    = (float*)d_out;                 // [16384][512]
  float* out_idx  = out_q + (size_t)NROWS * D;     // [16384] as float
  float* out_loss = out_idx + NROWS;               // [1]

  hipMemsetAsync(wsmin, 0xFF, (size_t)NROWS * 8, stream);
  hipMemsetAsync(out_loss, 0, sizeof(float), stream);
  vq_e2_kernel<<<NCODES / 4, 256, 0, stream>>>(embed, e2);
  vq_gemm_kernel<<<ROWBLKS * COLBLKS, 256, 0, stream>>>(x, embed, e2, wsmin);
  vq_finish_kernel<<<NROWS / 4, 256, 0, stream>>>(x, embed, wsmin, out_q,
                                                  out_idx, out_loss);
}

// Round 3
// 2738.161 us; speedup vs baseline: 10.2744x; 10.2744x over previous
//
#include <hip/hip_runtime.h>
#include <cstdint>
#include <cstddef>

#define D        512
#define NROWS    16384
#define NCODES   8192
#define BMM      128   // rows per block tile
#define BNN      128   // codes per block tile
#define BKK      16    // k chunk
#define NKC      (D / BKK)
#define COLBLKS  (NCODES / BNN)   // 64
#define ROWBLKS  (NROWS / BMM)    // 128

// ---------------------------------------------------------------------------
// Kernel 1: e2[c] = sum_d embed[c][d]^2.  One wave per code row.
// ---------------------------------------------------------------------------
__global__ void vq_e2_kernel(const float* __restrict__ embed,
                             float* __restrict__ e2) {
  const int w    = (blockIdx.x * blockDim.x + threadIdx.x) >> 6;
  const int lane = threadIdx.x & 63;
  const float* p = embed + (size_t)w * D + lane * 8;
  const float4 a = *(const float4*)p;
  const float4 b = *(const float4*)(p + 4);
  float s = a.x * a.x + a.y * a.y + a.z * a.z + a.w * a.w +
            b.x * b.x + b.y * b.y + b.z * b.z + b.w * b.w;
#pragma unroll
  for (int m = 32; m >= 1; m >>= 1) s += __shfl_xor(s, m, 64);
  if (lane == 0) e2[w] = s;
}

// order-preserving fp32 -> u32 key (ascending float -> ascending uint)
__device__ __forceinline__ unsigned int fkey(float f) {
  unsigned int u = __float_as_uint(f);
  return (u & 0x80000000u) ? ~u : (u | 0x80000000u);
}

// ---------------------------------------------------------------------------
// Kernel 2: streamed fp32 GEMM tile (128x128, BK=16 double-buffered) computing
// dot(x_row, e_code); fused per-tile argmin of score = e2[c] - 2*dot,
// merged globally via atomicMin on packed (key<<32 | idx).
//   256 threads (4 waves). Thread (tr=tid>>4, tc=tid&15) owns an 8x8 tile.
//   LDS: 2*2*16*132*4 = 33.8 KB.
//   __launch_bounds__(256,1): do NOT cap VGPRs — acc[8][8] needs ~130 regs;
//   round-2's (256,4) forced 64 VGPRs -> accumulator spilled to scratch
//   (67 GB WRITE_SIZE, 24.5 ms). 3 waves/SIMD at ~150 VGPR is plenty.
// ---------------------------------------------------------------------------
__global__ __launch_bounds__(256, 1) void vq_gemm_kernel(
    const float* __restrict__ x, const float* __restrict__ embed,
    const float* __restrict__ e2g, unsigned long long* __restrict__ wsmin) {
  __shared__ float as[2][BKK][BMM + 4];   // k-major, stride 132
  __shared__ float bs[2][BKK][BNN + 4];

  const int tid    = threadIdx.x;
  const int colBlk = blockIdx.x & (COLBLKS - 1);
  const int rowBlk = blockIdx.x >> 6;
  const int row0   = rowBlk * BMM;
  const int c0     = colBlk * BNN;
  const int tr     = tid >> 4;   // 0..15 (row group)
  const int tc     = tid & 15;   // 0..15 (col group)

  // staging: float4 f = 2*tid + l; m = f>>2 (0..127), kq = (f&3)*4
  float4 ra[2], rb[2];
  const int sm0 = (tid * 2) >> 2;          // row/code index for l=0
  const int sq0 = ((tid * 2) & 3) * 4;     // k offset for l=0
  const int sm1 = (tid * 2 + 1) >> 2;
  const int sq1 = ((tid * 2 + 1) & 3) * 4;

#define GLOB_LOAD(kc)                                                        \
  do {                                                                       \
    const int kb = (kc) * BKK;                                               \
    ra[0] = *(const float4*)(x + (size_t)(row0 + sm0) * D + kb + sq0);       \
    ra[1] = *(const float4*)(x + (size_t)(row0 + sm1) * D + kb + sq1);       \
    rb[0] = *(const float4*)(embed + (size_t)(c0 + sm0) * D + kb + sq0);     \
    rb[1] = *(const float4*)(embed + (size_t)(c0 + sm1) * D + kb + sq1);     \
  } while (0)

#define LDS_WRITE(buf)                                                       \
  do {                                                                       \
    as[buf][sq0 + 0][sm0] = ra[0].x; as[buf][sq0 + 1][sm0] = ra[0].y;        \
    as[buf][sq0 + 2][sm0] = ra[0].z; as[buf][sq0 + 3][sm0] = ra[0].w;        \
    as[buf][sq1 + 0][sm1] = ra[1].x; as[buf][sq1 + 1][sm1] = ra[1].y;        \
    as[buf][sq1 + 2][sm1] = ra[1].z; as[buf][sq1 + 3][sm1] = ra[1].w;        \
    bs[buf][sq0 + 0][sm0] = rb[0].x; bs[buf][sq0 + 1][sm0] = rb[0].y;        \
    bs[buf][sq0 + 2][sm0] = rb[0].z; bs[buf][sq0 + 3][sm0] = rb[0].w;        \
    bs[buf][sq1 + 0][sm1] = rb[1].x; bs[buf][sq1 + 1][sm1] = rb[1].y;        \
    bs[buf][sq1 + 2][sm1] = rb[1].z; bs[buf][sq1 + 3][sm1] = rb[1].w;        \
  } while (0)

  float acc[8][8];
#pragma unroll
  for (int i = 0; i < 8; ++i)
#pragma unroll
    for (int j = 0; j < 8; ++j) acc[i][j] = 0.f;

  GLOB_LOAD(0);
  LDS_WRITE(0);
  __syncthreads();

  int cur = 0;
  for (int kc = 0; kc < NKC; ++kc) {
    if (kc + 1 < NKC) GLOB_LOAD(kc + 1);   // vmem in flight over compute
#pragma unroll
    for (int k = 0; k < BKK; ++k) {
      float a[8], b[8];
      *(float4*)&a[0] = *(const float4*)&as[cur][k][tr * 8];
      *(float4*)&a[4] = *(const float4*)&as[cur][k][tr * 8 + 4];
      *(float4*)&b[0] = *(const float4*)&bs[cur][k][tc * 8];
      *(float4*)&b[4] = *(const float4*)&bs[cur][k][tc * 8 + 4];
#pragma unroll
      for (int i = 0; i < 8; ++i)
#pragma unroll
        for (int j = 0; j < 8; ++j) acc[i][j] = fmaf(a[i], b[j], acc[i][j]);
    }
    if (kc + 1 < NKC) {
      LDS_WRITE(cur ^ 1);   // other buffer: free since barrier of kc-1
      __syncthreads();
    }
    cur ^= 1;
  }

  // epilogue: score = e2 - 2*dot ; per-row argmin over this 128-code tile
  float e2a[8];
  *(float4*)&e2a[0] = *(const float4*)(e2g + c0 + tc * 8);
  *(float4*)&e2a[4] = *(const float4*)(e2g + c0 + tc * 8 + 4);
#pragma unroll
  for (int i = 0; i < 8; ++i) {
    float bv = 3.4e38f;
    int   bi = 0;
#pragma unroll
    for (int j = 0; j < 8; ++j) {
      const float s = fmaf(-2.f, acc[i][j], e2a[j]);
      if (s < bv) { bv = s; bi = c0 + tc * 8 + j; }   // strict <: lowest idx
    }
    // reduce across the 16 tc-lanes (same tr) — contiguous 16-lane group
#pragma unroll
    for (int m = 8; m >= 1; m >>= 1) {
      const float ov = __shfl_xor(bv, m, 64);
      const int   oi = __shfl_xor(bi, m, 64);
      if (ov < bv || (ov == bv && oi < bi)) { bv = ov; bi = oi; }
    }
    if (tc == 0) {
      const unsigned long long packed =
          ((unsigned long long)fkey(bv) << 32) | (unsigned int)bi;
      atomicMin(&wsmin[row0 + tr * 8 + i], packed);
    }
  }
#undef GLOB_LOAD
#undef LDS_WRITE
}

// ---------------------------------------------------------------------------
// Kernel 3: gather winning rows, write q, idx (as float), commit loss.
// One wave per row.
// ---------------------------------------------------------------------------
__global__ void vq_finish_kernel(const float* __restrict__ x,
                                 const float* __restrict__ embed,
                                 const unsigned long long* __restrict__ wsmin,
                                 float* __restrict__ out_q,
                                 float* __restrict__ out_idx,
                                 float* __restrict__ out_loss) {
  const int row  = blockIdx.x * 4 + (threadIdx.x >> 6);
  const int lane = threadIdx.x & 63;
  const int idx  = (int)(wsmin[row] & 0xFFFFFFFFull);
  if (lane == 0) out_idx[row] = (float)idx;

  const float* ep = embed + (size_t)idx * D + lane * 8;
  const float* xp = x + (size_t)row * D + lane * 8;
  float* qp       = out_q + (size_t)row * D + lane * 8;

  const float4 e0 = *(const float4*)ep;
  const float4 e1 = *(const float4*)(ep + 4);
  const float4 x0 = *(const float4*)xp;
  const float4 x1 = *(const float4*)(xp + 4);
  *(float4*)qp       = e0;   // x + sg(q - x) == q numerically
  *(float4*)(qp + 4) = e1;

  float l = (e0.x - x0.x) * (e0.x - x0.x) + (e0.y - x0.y) * (e0.y - x0.y) +
            (e0.z - x0.z) * (e0.z - x0.z) + (e0.w - x0.w) * (e0.w - x0.w) +
            (e1.x - x1.x) * (e1.x - x1.x) + (e1.y - x1.y) * (e1.y - x1.y) +
            (e1.z - x1.z) * (e1.z - x1.z) + (e1.w - x1.w) * (e1.w - x1.w);
#pragma unroll
  for (int m = 32; m >= 1; m >>= 1) l += __shfl_xor(l, m, 64);
  if (lane == 0)
    atomicAdd(out_loss, l * (1.f / (float)((size_t)NROWS * D)));
}

// ---------------------------------------------------------------------------
extern "C" void kernel_launch(void* const* d_in, const int* in_sizes, int n_in,
                              void* d_out, int out_size, void* d_ws,
                              size_t ws_size, hipStream_t stream) {
  (void)in_sizes; (void)n_in; (void)out_size; (void)ws_size;
  const float* x     = (const float*)d_in[0];
  const float* embed = (const float*)d_in[1];

  unsigned long long* wsmin = (unsigned long long*)d_ws;       // 16384 * 8 B
  float* e2 = (float*)((char*)d_ws + (size_t)NROWS * 8);       // 8192 * 4 B

  float* out_q    = (float*)d_out;                 // [16384][512]
  float* out_idx  = out_q + (size_t)NROWS * D;     // [16384] as float
  float* out_loss = out_idx + NROWS;               // [1]

  hipMemsetAsync(wsmin, 0xFF, (size_t)NROWS * 8, stream);
  hipMemsetAsync(out_loss, 0, sizeof(float), stream);
  vq_e2_kernel<<<NCODES / 4, 256, 0, stream>>>(embed, e2);
  vq_gemm_kernel<<<ROWBLKS * COLBLKS, 256, 0, stream>>>(x, embed, e2, wsmin);
  vq_finish_kernel<<<NROWS / 4, 256, 0, stream>>>(x, embed, wsmin, out_q,
                                                  out_idx, out_loss);
}

// Round 4
// 2521.211 us; speedup vs baseline: 11.1585x; 1.0860x over previous
//
#include <hip/hip_runtime.h>
#include <cstdint>
#include <cstddef>

#define D        512
#define NROWS    16384
#define NCODES   8192
#define BMM      128   // rows per block tile
#define BNN      128   // codes per block tile
#define BKK      16    // k chunk
#define NKC      (D / BKK)
#define COLBLKS  (NCODES / BNN)   // 64
#define ROWBLKS  (NROWS / BMM)    // 128

// ---------------------------------------------------------------------------
// Kernel 1: e2[c] = sum_d embed[c][d]^2.  One wave per code row.
// ---------------------------------------------------------------------------
__global__ void vq_e2_kernel(const float* __restrict__ embed,
                             float* __restrict__ e2) {
  const int w    = (blockIdx.x * blockDim.x + threadIdx.x) >> 6;
  const int lane = threadIdx.x & 63;
  const float* p = embed + (size_t)w * D + lane * 8;
  const float4 a = *(const float4*)p;
  const float4 b = *(const float4*)(p + 4);
  float s = a.x * a.x + a.y * a.y + a.z * a.z + a.w * a.w +
            b.x * b.x + b.y * b.y + b.z * b.z + b.w * b.w;
#pragma unroll
  for (int m = 32; m >= 1; m >>= 1) s += __shfl_xor(s, m, 64);
  if (lane == 0) e2[w] = s;
}

// order-preserving fp32 -> u32 key (ascending float -> ascending uint)
__device__ __forceinline__ unsigned int fkey(float f) {
  unsigned int u = __float_as_uint(f);
  return (u & 0x80000000u) ? ~u : (u | 0x80000000u);
}

// ---------------------------------------------------------------------------
// Kernel 2: streamed fp32 GEMM tile (128x128, BK=16 double-buffered).
//   Thread (tr,tc) owns SPLIT 8x8 tile: rows {tr*4..+3, 64+tr*4..+3},
//   cols {tc*4..+3, 64+tc*4..+3}.  16B-stride frag reads -> no 4-way bank
//   conflicts (round 3: 32B stride cost 1.678e8 conflict cycles, VALUBusy 55%).
//   score = e2[c] - 2*dot; global merge via atomicMin on (key<<32 | idx).
// ---------------------------------------------------------------------------
__global__ __launch_bounds__(256, 1) void vq_gemm_kernel(
    const float* __restrict__ x, const float* __restrict__ embed,
    const float* __restrict__ e2g, unsigned long long* __restrict__ wsmin) {
  __shared__ float as[2][BKK][BMM + 4];   // k-major, stride 132
  __shared__ float bs[2][BKK][BNN + 4];

  const int tid    = threadIdx.x;
  const int colBlk = blockIdx.x & (COLBLKS - 1);
  const int rowBlk = blockIdx.x >> 6;
  const int row0   = rowBlk * BMM;
  const int c0     = colBlk * BNN;
  const int tr     = tid >> 4;   // 0..15 (row group)
  const int tc     = tid & 15;   // 0..15 (col group)

  float4 ra[2], rb[2];
  const int sm0 = (tid * 2) >> 2;          // row/code index for l=0
  const int sq0 = ((tid * 2) & 3) * 4;     // k offset for l=0
  const int sm1 = (tid * 2 + 1) >> 2;
  const int sq1 = ((tid * 2 + 1) & 3) * 4;

#define GLOB_LOAD(kc)                                                        \
  do {                                                                       \
    const int kb = (kc) * BKK;                                               \
    ra[0] = *(const float4*)(x + (size_t)(row0 + sm0) * D + kb + sq0);       \
    ra[1] = *(const float4*)(x + (size_t)(row0 + sm1) * D + kb + sq1);       \
    rb[0] = *(const float4*)(embed + (size_t)(c0 + sm0) * D + kb + sq0);     \
    rb[1] = *(const float4*)(embed + (size_t)(c0 + sm1) * D + kb + sq1);     \
  } while (0)

#define LDS_WRITE(buf)                                                       \
  do {                                                                       \
    as[buf][sq0 + 0][sm0] = ra[0].x; as[buf][sq0 + 1][sm0] = ra[0].y;        \
    as[buf][sq0 + 2][sm0] = ra[0].z; as[buf][sq0 + 3][sm0] = ra[0].w;        \
    as[buf][sq1 + 0][sm1] = ra[1].x; as[buf][sq1 + 1][sm1] = ra[1].y;        \
    as[buf][sq1 + 2][sm1] = ra[1].z; as[buf][sq1 + 3][sm1] = ra[1].w;        \
    bs[buf][sq0 + 0][sm0] = rb[0].x; bs[buf][sq0 + 1][sm0] = rb[0].y;        \
    bs[buf][sq0 + 2][sm0] = rb[0].z; bs[buf][sq0 + 3][sm0] = rb[0].w;        \
    bs[buf][sq1 + 0][sm1] = rb[1].x; bs[buf][sq1 + 1][sm1] = rb[1].y;        \
    bs[buf][sq1 + 2][sm1] = rb[1].z; bs[buf][sq1 + 3][sm1] = rb[1].w;        \
  } while (0)

  float acc[8][8];
#pragma unroll
  for (int i = 0; i < 8; ++i)
#pragma unroll
    for (int j = 0; j < 8; ++j) acc[i][j] = 0.f;

  GLOB_LOAD(0);
  LDS_WRITE(0);
  __syncthreads();

  int cur = 0;
  for (int kc = 0; kc < NKC; ++kc) {
    if (kc + 1 < NKC) GLOB_LOAD(kc + 1);   // vmem in flight over compute
#pragma unroll
    for (int k = 0; k < BKK; ++k) {
      float a[8], b[8];
      *(float4*)&a[0] = *(const float4*)&as[cur][k][tr * 4];        // 16B stride
      *(float4*)&a[4] = *(const float4*)&as[cur][k][64 + tr * 4];
      *(float4*)&b[0] = *(const float4*)&bs[cur][k][tc * 4];
      *(float4*)&b[4] = *(const float4*)&bs[cur][k][64 + tc * 4];
#pragma unroll
      for (int i = 0; i < 8; ++i)
#pragma unroll
        for (int j = 0; j < 8; ++j) acc[i][j] = fmaf(a[i], b[j], acc[i][j]);
    }
    if (kc + 1 < NKC) {
      LDS_WRITE(cur ^ 1);   // other buffer: free since barrier of kc-1
      __syncthreads();
    }
    cur ^= 1;
  }

  // epilogue: score = e2 - 2*dot ; per-row argmin over this 128-code tile
  float e2a[8];
  *(float4*)&e2a[0] = *(const float4*)(e2g + c0 + tc * 4);
  *(float4*)&e2a[4] = *(const float4*)(e2g + c0 + 64 + tc * 4);
#pragma unroll
  for (int i = 0; i < 8; ++i) {
    const int rowi = (i < 4) ? (tr * 4 + i) : (64 + tr * 4 + (i - 4));
    float bv = 3.4e38f;
    int   bi = 0;
#pragma unroll
    for (int j = 0; j < 8; ++j) {   // cols ascend with j -> strict < keeps lowest idx
      const int colj = (j < 4) ? (tc * 4 + j) : (64 + tc * 4 + (j - 4));
      const float s = fmaf(-2.f, acc[i][j], e2a[j]);
      if (s < bv) { bv = s; bi = c0 + colj; }
    }
    // reduce across the 16 tc-lanes (same tr) — contiguous 16-lane group
#pragma unroll
    for (int m = 8; m >= 1; m >>= 1) {
      const float ov = __shfl_xor(bv, m, 64);
      const int   oi = __shfl_xor(bi, m, 64);
      if (ov < bv || (ov == bv && oi < bi)) { bv = ov; bi = oi; }
    }
    if (tc == 0) {
      const unsigned long long packed =
          ((unsigned long long)fkey(bv) << 32) | (unsigned int)bi;
      atomicMin(&wsmin[row0 + rowi], packed);
    }
  }
#undef GLOB_LOAD
#undef LDS_WRITE
}

// ---------------------------------------------------------------------------
// Kernel 3: gather winning rows, write q, idx (as float), commit loss.
// One wave per row.
// ---------------------------------------------------------------------------
__global__ void vq_finish_kernel(const float* __restrict__ x,
                                 const float* __restrict__ embed,
                                 const unsigned long long* __restrict__ wsmin,
                                 float* __restrict__ out_q,
                                 float* __restrict__ out_idx,
                                 float* __restrict__ out_loss) {
  const int row  = blockIdx.x * 4 + (threadIdx.x >> 6);
  const int lane = threadIdx.x & 63;
  const int idx  = (int)(wsmin[row] & 0xFFFFFFFFull);
  if (lane == 0) out_idx[row] = (float)idx;

  const float* ep = embed + (size_t)idx * D + lane * 8;
  const float* xp = x + (size_t)row * D + lane * 8;
  float* qp       = out_q + (size_t)row * D + lane * 8;

  const float4 e0 = *(const float4*)ep;
  const float4 e1 = *(const float4*)(ep + 4);
  const float4 x0 = *(const float4*)xp;
  const float4 x1 = *(const float4*)(xp + 4);
  *(float4*)qp       = e0;   // x + sg(q - x) == q numerically
  *(float4*)(qp + 4) = e1;

  float l = (e0.x - x0.x) * (e0.x - x0.x) + (e0.y - x0.y) * (e0.y - x0.y) +
            (e0.z - x0.z) * (e0.z - x0.z) + (e0.w - x0.w) * (e0.w - x0.w) +
            (e1.x - x1.x) * (e1.x - x1.x) + (e1.y - x1.y) * (e1.y - x1.y) +
            (e1.z - x1.z) * (e1.z - x1.z) + (e1.w - x1.w) * (e1.w - x1.w);
#pragma unroll
  for (int m = 32; m >= 1; m >>= 1) l += __shfl_xor(l, m, 64);
  if (lane == 0)
    atomicAdd(out_loss, l * (1.f / (float)((size_t)NROWS * D)));
}

// ---------------------------------------------------------------------------
extern "C" void kernel_launch(void* const* d_in, const int* in_sizes, int n_in,
                              void* d_out, int out_size, void* d_ws,
                              size_t ws_size, hipStream_t stream) {
  (void)in_sizes; (void)n_in; (void)out_size; (void)ws_size;
  const float* x     = (const float*)d_in[0];
  const float* embed = (const float*)d_in[1];

  unsigned long long* wsmin = (unsigned long long*)d_ws;       // 16384 * 8 B
  float* e2 = (float*)((char*)d_ws + (size_t)NROWS * 8);       // 8192 * 4 B

  float* out_q    = (float*)d_out;                 // [16384][512]
  float* out_idx  = out_q + (size_t)NROWS * D;     // [16384] as float
  float* out_loss = out_idx + NROWS;               // [1]

  hipMemsetAsync(wsmin, 0xFF, (size_t)NROWS * 8, stream);
  hipMemsetAsync(out_loss, 0, sizeof(float), stream);
  vq_e2_kernel<<<NCODES / 4, 256, 0, stream>>>(embed, e2);
  vq_gemm_kernel<<<ROWBLKS * COLBLKS, 256, 0, stream>>>(x, embed, e2, wsmin);
  vq_finish_kernel<<<NROWS / 4, 256, 0, stream>>>(x, embed, wsmin, out_q,
                                                  out_idx, out_loss);
}

// Round 5
// 1442.074 us; speedup vs baseline: 19.5087x; 1.7483x over previous
//
#include <hip/hip_runtime.h>
#include <cstdint>
#include <cstddef>

#define D       512
#define NROWS   16384
#define NCODES  8192
#define BM      256
#define BN      256
#define BK      32
#define NKC     (D / BK)       // 16
#define RB      (NROWS / BM)   // 64
#define CB      (NCODES / BN)  // 32
#define NBLK    (RB * CB)      // 2048
#define EPS     0.02f

typedef __attribute__((ext_vector_type(8))) short short8;  // 8 bf16
typedef __attribute__((ext_vector_type(4))) float f32x4;
typedef unsigned long long u64;

#define ROWB   80                 // bytes per LDS plane row (64 data + 16 pad)
#define PLANE  (BM * ROWB)        // 20480
#define XH 0
#define XL (1 * PLANE)
#define EH (2 * PLANE)
#define EL (3 * PLANE)
#define LDSZ (4 * PLANE)          // 81920

// order-preserving fp32 <-> u32 key
__device__ __forceinline__ uint32_t fkey(float f) {
  uint32_t u = __float_as_uint(f);
  return (u & 0x80000000u) ? ~u : (u | 0x80000000u);
}
__device__ __forceinline__ float unfkey(uint32_t k) {
  uint32_t u = (k & 0x80000000u) ? (k & 0x7FFFFFFFu) : ~k;
  return __uint_as_float(u);
}
// round-to-nearest bf16, returned as high-aligned fp32 bits
__device__ __forceinline__ uint32_t bfhi(float f) {
  uint32_t u = __float_as_uint(f);
  return (u + 0x7FFFu + ((u >> 16) & 1u)) & 0xFFFF0000u;
}

// ---------------------------------------------------------------------------
__global__ void vq_e2_kernel(const float* __restrict__ embed,
                             float* __restrict__ e2) {
  const int w    = (blockIdx.x * blockDim.x + threadIdx.x) >> 6;
  const int lane = threadIdx.x & 63;
  const float* p = embed + (size_t)w * D + lane * 8;
  const float4 a = *(const float4*)p;
  const float4 b = *(const float4*)(p + 4);
  float s = a.x * a.x + a.y * a.y + a.z * a.z + a.w * a.w +
            b.x * b.x + b.y * b.y + b.z * b.z + b.w * b.w;
#pragma unroll
  for (int m = 32; m >= 1; m >>= 1) s += __shfl_xor(s, m, 64);
  if (lane == 0) e2[w] = s;
}

// ---------------------------------------------------------------------------
// MFMA distance kernel: 3-term bf16-split emulation of fp32 dot.
// Block 256x256, 512 thr (8 waves as 2x4; wave tile 128x64).
// Tracks exact global top-2 score per row via atomicMin protocol.
// ---------------------------------------------------------------------------
__global__ __launch_bounds__(512, 1) void vq_mfma_kernel(
    const float* __restrict__ x, const float* __restrict__ embed,
    const float* __restrict__ e2g,
    u64* __restrict__ min1g, u64* __restrict__ min2g) {
  __shared__ __align__(16) char smem[LDSZ];

  const int tid  = threadIdx.x;
  const int lane = tid & 63;
  const int w    = tid >> 6;
  const int wrow = (w >> 2) * 128;   // 0 or 128
  const int wc   = w & 3;
  const int wcol = wc * 64;

  // XCD-aware bijective block swizzle (2048 % 8 == 0)
  const int xcd = blockIdx.x & 7;
  const int id  = blockIdx.x >> 3;          // 0..255
  const int rb  = id >> 2;                  // 0..63
  const int cb  = xcd * 4 + (id & 3);       // 0..31
  const int row0 = rb * BM;
  const int c0   = cb * BN;

  const int srow = tid >> 3;                // 0..63 (+64*i)
  const int skq  = (tid & 7) * 4;           // 0,4,..,28

  f32x4 acc[8][4];
#pragma unroll
  for (int i = 0; i < 8; ++i)
#pragma unroll
    for (int j = 0; j < 4; ++j) acc[i][j] = (f32x4)0.f;

  float4 rx[4], re[4];

#define GLOB_LOAD(kc)                                                         \
  do {                                                                        \
    const int kb = (kc) * BK;                                                 \
    _Pragma("unroll") for (int i = 0; i < 4; ++i)                             \
      rx[i] = *(const float4*)(x + (size_t)(row0 + srow + i * 64) * D + kb + skq); \
    _Pragma("unroll") for (int i = 0; i < 4; ++i)                             \
      re[i] = *(const float4*)(embed + (size_t)(c0 + srow + i * 64) * D + kb + skq); \
  } while (0)

#define CONV_WRITE()                                                          \
  do {                                                                        \
    _Pragma("unroll") for (int i = 0; i < 4; ++i) {                           \
      const int off = (srow + i * 64) * ROWB + skq * 2;                       \
      uint32_t h0 = bfhi(rx[i].x), h1 = bfhi(rx[i].y);                        \
      uint32_t h2 = bfhi(rx[i].z), h3 = bfhi(rx[i].w);                        \
      float l0 = rx[i].x - __uint_as_float(h0);                               \
      float l1 = rx[i].y - __uint_as_float(h1);                               \
      float l2 = rx[i].z - __uint_as_float(h2);                               \
      float l3 = rx[i].w - __uint_as_float(h3);                               \
      *(uint2*)(smem + XH + off) = make_uint2(h1 | (h0 >> 16), h3 | (h2 >> 16)); \
      *(uint2*)(smem + XL + off) = make_uint2(bfhi(l1) | (bfhi(l0) >> 16),    \
                                              bfhi(l3) | (bfhi(l2) >> 16));   \
      h0 = bfhi(re[i].x); h1 = bfhi(re[i].y);                                 \
      h2 = bfhi(re[i].z); h3 = bfhi(re[i].w);                                 \
      l0 = re[i].x - __uint_as_float(h0);                                     \
      l1 = re[i].y - __uint_as_float(h1);                                     \
      l2 = re[i].z - __uint_as_float(h2);                                     \
      l3 = re[i].w - __uint_as_float(h3);                                     \
      *(uint2*)(smem + EH + off) = make_uint2(h1 | (h0 >> 16), h3 | (h2 >> 16)); \
      *(uint2*)(smem + EL + off) = make_uint2(bfhi(l1) | (bfhi(l0) >> 16),    \
                                              bfhi(l3) | (bfhi(l2) >> 16));   \
    }                                                                         \
  } while (0)

  GLOB_LOAD(0);

  const int fr  = lane & 15;        // frag row-within-tile
  const int fks = (lane >> 4) * 16; // frag k-slot byte offset

  for (int kc = 0; kc < NKC; ++kc) {
    if (kc) __syncthreads();        // all reads of chunk kc-1 done
    CONV_WRITE();
    __syncthreads();
    if (kc + 1 < NKC) GLOB_LOAD(kc + 1);   // in flight across the MFMA block

    short8 bh[4], bl[4];
#pragma unroll
    for (int j = 0; j < 4; ++j) {
      const int boff = (wcol + j * 16 + fr) * ROWB + fks;
      bh[j] = *(const short8*)(smem + EH + boff);
      bl[j] = *(const short8*)(smem + EL + boff);
    }
#pragma unroll
    for (int i = 0; i < 8; ++i) {
      const int aoff = (wrow + i * 16 + fr) * ROWB + fks;
      const short8 ah = *(const short8*)(smem + XH + aoff);
      const short8 al = *(const short8*)(smem + XL + aoff);
#pragma unroll
      for (int j = 0; j < 4; ++j) {
        acc[i][j] = __builtin_amdgcn_mfma_f32_16x16x32_bf16(ah, bh[j], acc[i][j], 0, 0, 0);
        acc[i][j] = __builtin_amdgcn_mfma_f32_16x16x32_bf16(ah, bl[j], acc[i][j], 0, 0, 0);
        acc[i][j] = __builtin_amdgcn_mfma_f32_16x16x32_bf16(al, bh[j], acc[i][j], 0, 0, 0);
      }
    }
  }

  // ---- epilogue: per-row top-2 over this block's 256 codes ----
  float e2v[4];
#pragma unroll
  for (int j = 0; j < 4; ++j) e2v[j] = e2g[c0 + wcol + j * 16 + fr];

  __syncthreads();                       // all MFMA LDS reads done; reuse smem
  u64 (*mb)[4][2] = (u64(*)[4][2])smem;  // [256 rows][4 wavecols][min1,min2]

#pragma unroll
  for (int i = 0; i < 8; ++i) {
#pragma unroll
    for (int r = 0; r < 4; ++r) {
      float v1 = 3.4e38f, v2 = 3.4e38f;
      int c1 = 0;
#pragma unroll
      for (int j = 0; j < 4; ++j) {
        const float s = fmaf(-2.f, acc[i][j][r], e2v[j]);
        if (s < v1) { v2 = v1; v1 = s; c1 = c0 + wcol + j * 16 + fr; }
        else if (s < v2) v2 = s;
      }
      u64 p1 = ((u64)fkey(v1) << 32) | (uint32_t)c1;
      uint32_t k2 = fkey(v2);
#pragma unroll
      for (int m = 8; m >= 1; m >>= 1) {   // merge across 16-lane group
        const u64 o1 = __shfl_xor(p1, m, 64);
        const uint32_t o2 = __shfl_xor(k2, m, 64);
        const u64 lo = p1 < o1 ? p1 : o1;
        const u64 hi = p1 < o1 ? o1 : p1;
        uint32_t nk = k2 < o2 ? k2 : o2;
        const uint32_t hk = (uint32_t)(hi >> 32);
        k2 = nk < hk ? nk : hk;
        p1 = lo;
      }
      if ((lane & 15) == 0) {
        const int lrow = wrow + i * 16 + (lane >> 4) * 4 + r;
        mb[lrow][wc][0] = p1;
        mb[lrow][wc][1] = ((u64)k2 << 32) | 0xFFFFFFFFull;
      }
    }
  }
  __syncthreads();

  if (tid < 256) {
    u64 m1 = mb[tid][0][0], m2 = mb[tid][0][1];
#pragma unroll
    for (int q = 1; q < 4; ++q) {
      const u64 a1 = mb[tid][q][0], a2 = mb[tid][q][1];
      const u64 nm1 = m1 < a1 ? m1 : a1;
      const u64 big = m1 < a1 ? a1 : m1;
      u64 nm2 = m2 < a2 ? m2 : a2;
      nm2 = nm2 < big ? nm2 : big;
      m1 = nm1; m2 = nm2;
    }
    // lock-free global top-2 merge
    const u64 old = atomicMin(&min1g[row0 + tid], m1);
    u64 push = m1 < old ? old : m1;       // max(m1, old)
    push = m2 < push ? m2 : push;
    atomicMin(&min2g[row0 + tid], push);
  }
#undef GLOB_LOAD
#undef CONV_WRITE
}

// ---------------------------------------------------------------------------
// Exact fp32 recheck for rows whose approx top-2 margin < EPS.
// One block per row; uniform early exit otherwise.
// ---------------------------------------------------------------------------
__global__ __launch_bounds__(256) void vq_recheck_kernel(
    const float* __restrict__ x, const float* __restrict__ embed,
    const float* __restrict__ e2g,
    u64* __restrict__ min1g, const u64* __restrict__ min2g) {
  const int row = blockIdx.x;
  const u64 m1 = min1g[row], m2 = min2g[row];
  const float f1 = unfkey((uint32_t)(m1 >> 32));
  const float f2 = unfkey((uint32_t)(m2 >> 32));
  if (f2 - f1 >= EPS) return;

  __shared__ float xs[D];
  __shared__ u64 red[256];
  const int t = threadIdx.x;
  xs[t]       = x[(size_t)row * D + t];
  xs[t + 256] = x[(size_t)row * D + 256 + t];
  __syncthreads();

  float bv = 3.4e38f;
  int   bi = 0;
  for (int c = t; c < NCODES; c += 256) {
    const float* ep = embed + (size_t)c * D;
    float d0 = 0.f, d1 = 0.f, d2 = 0.f, d3 = 0.f;
    for (int k = 0; k < D; k += 4) {
      const float4 ev = *(const float4*)(ep + k);
      const float4 xv = *(const float4*)&xs[k];
      d0 = fmaf(xv.x, ev.x, d0); d1 = fmaf(xv.y, ev.y, d1);
      d2 = fmaf(xv.z, ev.z, d2); d3 = fmaf(xv.w, ev.w, d3);
    }
    const float s = fmaf(-2.f, (d0 + d1) + (d2 + d3), e2g[c]);
    if (s < bv) { bv = s; bi = c; }   // c ascending: lowest idx on ties
  }
  red[t] = ((u64)fkey(bv) << 32) | (uint32_t)bi;
  __syncthreads();
  for (int m = 128; m >= 1; m >>= 1) {
    if (t < m) { const u64 o = red[t + m]; if (o < red[t]) red[t] = o; }
    __syncthreads();
  }
  if (t == 0) min1g[row] = red[0];
}

// ---------------------------------------------------------------------------
// Gather winning rows, write q, idx (as float), commit loss.
// ---------------------------------------------------------------------------
__global__ void vq_finish_kernel(const float* __restrict__ x,
                                 const float* __restrict__ embed,
                                 const u64* __restrict__ min1g,
                                 float* __restrict__ out_q,
                                 float* __restrict__ out_idx,
                                 float* __restrict__ out_loss) {
  const int row  = blockIdx.x * 4 + (threadIdx.x >> 6);
  const int lane = threadIdx.x & 63;
  const int idx  = (int)(min1g[row] & 0xFFFFFFFFull);
  if (lane == 0) out_idx[row] = (float)idx;

  const float* ep = embed + (size_t)idx * D + lane * 8;
  const float* xp = x + (size_t)row * D + lane * 8;
  float* qp       = out_q + (size_t)row * D + lane * 8;

  const float4 e0 = *(const float4*)ep;
  const float4 e1 = *(const float4*)(ep + 4);
  const float4 x0 = *(const float4*)xp;
  const float4 x1 = *(const float4*)(xp + 4);
  *(float4*)qp       = e0;   // x + sg(q - x) == q numerically
  *(float4*)(qp + 4) = e1;

  float l = (e0.x - x0.x) * (e0.x - x0.x) + (e0.y - x0.y) * (e0.y - x0.y) +
            (e0.z - x0.z) * (e0.z - x0.z) + (e0.w - x0.w) * (e0.w - x0.w) +
            (e1.x - x1.x) * (e1.x - x1.x) + (e1.y - x1.y) * (e1.y - x1.y) +
            (e1.z - x1.z) * (e1.z - x1.z) + (e1.w - x1.w) * (e1.w - x1.w);
#pragma unroll
  for (int m = 32; m >= 1; m >>= 1) l += __shfl_xor(l, m, 64);
  if (lane == 0)
    atomicAdd(out_loss, l * (1.f / (float)((size_t)NROWS * D)));
}

// ---------------------------------------------------------------------------
extern "C" void kernel_launch(void* const* d_in, const int* in_sizes, int n_in,
                              void* d_out, int out_size, void* d_ws,
                              size_t ws_size, hipStream_t stream) {
  (void)in_sizes; (void)n_in; (void)out_size; (void)ws_size;
  const float* x     = (const float*)d_in[0];
  const float* embed = (const float*)d_in[1];

  u64*  min1 = (u64*)d_ws;                                   // 16384 u64
  u64*  min2 = (u64*)((char*)d_ws + (size_t)NROWS * 8);      // 16384 u64
  float* e2  = (float*)((char*)d_ws + (size_t)NROWS * 16);   // 8192 f32

  float* out_q    = (float*)d_out;                 // [16384][512]
  float* out_idx  = out_q + (size_t)NROWS * D;     // [16384] as float
  float* out_loss = out_idx + NROWS;               // [1]

  hipMemsetAsync(d_ws, 0xFF, (size_t)NROWS * 16, stream);    // min1+min2
  hipMemsetAsync(out_loss, 0, sizeof(float), stream);
  vq_e2_kernel<<<NCODES / 4, 256, 0, stream>>>(embed, e2);
  vq_mfma_kernel<<<NBLK, 512, 0, stream>>>(x, embed, e2, min1, min2);
  vq_recheck_kernel<<<NROWS, 256, 0, stream>>>(x, embed, e2, min1, min2);
  vq_finish_kernel<<<NROWS / 4, 256, 0, stream>>>(x, embed, min1, out_q,
                                                  out_idx, out_loss);
}

// Round 6
// 717.971 us; speedup vs baseline: 39.1840x; 2.0085x over previous
//
#include <hip/hip_runtime.h>
#include <cstdint>
#include <cstddef>

#define D       512
#define NROWS   16384
#define NCODES  8192
#define BM      256
#define BN      256
#define BK      32
#define NKC     (D / BK)       // 16
#define RB      (NROWS / BM)   // 64
#define CB      (NCODES / BN)  // 32
#define NBLK    (RB * CB)      // 2048
#define EPS     0.02f
#define RCB     1024           // exact-recheck grid

typedef __attribute__((ext_vector_type(8))) short short8;  // 8 bf16
typedef __attribute__((ext_vector_type(4))) float f32x4;
typedef unsigned long long u64;

#define ROWB   80                 // bytes per LDS plane row (64 data + 16 pad)
#define PLANE  (BM * ROWB)        // 20480
#define XH 0
#define XL (1 * PLANE)
#define EH (2 * PLANE)
#define EL (3 * PLANE)
#define LDSZ (4 * PLANE)          // 81920

// order-preserving fp32 <-> u32 key
__device__ __forceinline__ uint32_t fkey(float f) {
  uint32_t u = __float_as_uint(f);
  return (u & 0x80000000u) ? ~u : (u | 0x80000000u);
}
__device__ __forceinline__ float unfkey(uint32_t k) {
  uint32_t u = (k & 0x80000000u) ? (k & 0x7FFFFFFFu) : ~k;
  return __uint_as_float(u);
}
// round-to-nearest bf16, returned as high-aligned fp32 bits
__device__ __forceinline__ uint32_t bfhi(float f) {
  uint32_t u = __float_as_uint(f);
  return (u + 0x7FFFu + ((u >> 16) & 1u)) & 0xFFFF0000u;
}

// ---------------------------------------------------------------------------
__global__ void vq_e2_kernel(const float* __restrict__ embed,
                             float* __restrict__ e2) {
  const int w    = (blockIdx.x * blockDim.x + threadIdx.x) >> 6;
  const int lane = threadIdx.x & 63;
  const float* p = embed + (size_t)w * D + lane * 8;
  const float4 a = *(const float4*)p;
  const float4 b = *(const float4*)(p + 4);
  float s = a.x * a.x + a.y * a.y + a.z * a.z + a.w * a.w +
            b.x * b.x + b.y * b.y + b.z * b.z + b.w * b.w;
#pragma unroll
  for (int m = 32; m >= 1; m >>= 1) s += __shfl_xor(s, m, 64);
  if (lane == 0) e2[w] = s;
}

// ---------------------------------------------------------------------------
// MFMA distance kernel: 3-term bf16-split emulation of fp32 dot.
// Block 256x256, 512 thr (8 waves as 2x4; wave tile 128x64).
// Tracks exact global top-2 score per row via atomicMin protocol.
// ---------------------------------------------------------------------------
__global__ __launch_bounds__(512, 1) void vq_mfma_kernel(
    const float* __restrict__ x, const float* __restrict__ embed,
    const float* __restrict__ e2g,
    u64* __restrict__ min1g, u64* __restrict__ min2g) {
  __shared__ __align__(16) char smem[LDSZ];

  const int tid  = threadIdx.x;
  const int lane = tid & 63;
  const int w    = tid >> 6;
  const int wrow = (w >> 2) * 128;   // 0 or 128
  const int wc   = w & 3;
  const int wcol = wc * 64;

  // XCD-aware bijective block swizzle (2048 % 8 == 0)
  const int xcd = blockIdx.x & 7;
  const int id  = blockIdx.x >> 3;          // 0..255
  const int rb  = id >> 2;                  // 0..63
  const int cb  = xcd * 4 + (id & 3);       // 0..31
  const int row0 = rb * BM;
  const int c0   = cb * BN;

  const int srow = tid >> 3;                // 0..63 (+64*i)
  const int skq  = (tid & 7) * 4;           // 0,4,..,28

  f32x4 acc[8][4];
#pragma unroll
  for (int i = 0; i < 8; ++i)
#pragma unroll
    for (int j = 0; j < 4; ++j) acc[i][j] = (f32x4)0.f;

  float4 rx[4], re[4];

#define GLOB_LOAD(kc)                                                         \
  do {                                                                        \
    const int kb = (kc) * BK;                                                 \
    _Pragma("unroll") for (int i = 0; i < 4; ++i)                             \
      rx[i] = *(const float4*)(x + (size_t)(row0 + srow + i * 64) * D + kb + skq); \
    _Pragma("unroll") for (int i = 0; i < 4; ++i)                             \
      re[i] = *(const float4*)(embed + (size_t)(c0 + srow + i * 64) * D + kb + skq); \
  } while (0)

#define CONV_WRITE()                                                          \
  do {                                                                        \
    _Pragma("unroll") for (int i = 0; i < 4; ++i) {                           \
      const int off = (srow + i * 64) * ROWB + skq * 2;                       \
      uint32_t h0 = bfhi(rx[i].x), h1 = bfhi(rx[i].y);                        \
      uint32_t h2 = bfhi(rx[i].z), h3 = bfhi(rx[i].w);                        \
      float l0 = rx[i].x - __uint_as_float(h0);                               \
      float l1 = rx[i].y - __uint_as_float(h1);                               \
      float l2 = rx[i].z - __uint_as_float(h2);                               \
      float l3 = rx[i].w - __uint_as_float(h3);                               \
      *(uint2*)(smem + XH + off) = make_uint2(h1 | (h0 >> 16), h3 | (h2 >> 16)); \
      *(uint2*)(smem + XL + off) = make_uint2(bfhi(l1) | (bfhi(l0) >> 16),    \
                                              bfhi(l3) | (bfhi(l2) >> 16));   \
      h0 = bfhi(re[i].x); h1 = bfhi(re[i].y);                                 \
      h2 = bfhi(re[i].z); h3 = bfhi(re[i].w);                                 \
      l0 = re[i].x - __uint_as_float(h0);                                     \
      l1 = re[i].y - __uint_as_float(h1);                                     \
      l2 = re[i].z - __uint_as_float(h2);                                     \
      l3 = re[i].w - __uint_as_float(h3);                                     \
      *(uint2*)(smem + EH + off) = make_uint2(h1 | (h0 >> 16), h3 | (h2 >> 16)); \
      *(uint2*)(smem + EL + off) = make_uint2(bfhi(l1) | (bfhi(l0) >> 16),    \
                                              bfhi(l3) | (bfhi(l2) >> 16));   \
    }                                                                         \
  } while (0)

  GLOB_LOAD(0);

  const int fr  = lane & 15;        // frag row-within-tile
  const int fks = (lane >> 4) * 16; // frag k-slot byte offset

  for (int kc = 0; kc < NKC; ++kc) {
    if (kc) __syncthreads();        // all reads of chunk kc-1 done
    CONV_WRITE();
    __syncthreads();
    if (kc + 1 < NKC) GLOB_LOAD(kc + 1);   // in flight across the MFMA block

    short8 bh[4], bl[4];
#pragma unroll
    for (int j = 0; j < 4; ++j) {
      const int boff = (wcol + j * 16 + fr) * ROWB + fks;
      bh[j] = *(const short8*)(smem + EH + boff);
      bl[j] = *(const short8*)(smem + EL + boff);
    }
#pragma unroll
    for (int i = 0; i < 8; ++i) {
      const int aoff = (wrow + i * 16 + fr) * ROWB + fks;
      const short8 ah = *(const short8*)(smem + XH + aoff);
      const short8 al = *(const short8*)(smem + XL + aoff);
#pragma unroll
      for (int j = 0; j < 4; ++j) {
        acc[i][j] = __builtin_amdgcn_mfma_f32_16x16x32_bf16(ah, bh[j], acc[i][j], 0, 0, 0);
        acc[i][j] = __builtin_amdgcn_mfma_f32_16x16x32_bf16(ah, bl[j], acc[i][j], 0, 0, 0);
        acc[i][j] = __builtin_amdgcn_mfma_f32_16x16x32_bf16(al, bh[j], acc[i][j], 0, 0, 0);
      }
    }
  }

  // ---- epilogue: per-row top-2 over this block's 256 codes ----
  float e2v[4];
#pragma unroll
  for (int j = 0; j < 4; ++j) e2v[j] = e2g[c0 + wcol + j * 16 + fr];

  __syncthreads();                       // all MFMA LDS reads done; reuse smem
  u64 (*mb)[4][2] = (u64(*)[4][2])smem;  // [256 rows][4 wavecols][min1,min2]

#pragma unroll
  for (int i = 0; i < 8; ++i) {
#pragma unroll
    for (int r = 0; r < 4; ++r) {
      float v1 = 3.4e38f, v2 = 3.4e38f;
      int c1 = 0;
#pragma unroll
      for (int j = 0; j < 4; ++j) {
        const float s = fmaf(-2.f, acc[i][j][r], e2v[j]);
        if (s < v1) { v2 = v1; v1 = s; c1 = c0 + wcol + j * 16 + fr; }
        else if (s < v2) v2 = s;
      }
      u64 p1 = ((u64)fkey(v1) << 32) | (uint32_t)c1;
      uint32_t k2 = fkey(v2);
#pragma unroll
      for (int m = 8; m >= 1; m >>= 1) {   // merge across 16-lane group
        const u64 o1 = __shfl_xor(p1, m, 64);
        const uint32_t o2 = __shfl_xor(k2, m, 64);
        const u64 lo = p1 < o1 ? p1 : o1;
        const u64 hi = p1 < o1 ? o1 : p1;
        uint32_t nk = k2 < o2 ? k2 : o2;
        const uint32_t hk = (uint32_t)(hi >> 32);
        k2 = nk < hk ? nk : hk;
        p1 = lo;
      }
      if ((lane & 15) == 0) {
        const int lrow = wrow + i * 16 + (lane >> 4) * 4 + r;
        mb[lrow][wc][0] = p1;
        mb[lrow][wc][1] = ((u64)k2 << 32) | 0xFFFFFFFFull;
      }
    }
  }
  __syncthreads();

  if (tid < 256) {
    u64 m1 = mb[tid][0][0], m2 = mb[tid][0][1];
#pragma unroll
    for (int q = 1; q < 4; ++q) {
      const u64 a1 = mb[tid][q][0], a2 = mb[tid][q][1];
      const u64 nm1 = m1 < a1 ? m1 : a1;
      const u64 big = m1 < a1 ? a1 : m1;
      u64 nm2 = m2 < a2 ? m2 : a2;
      nm2 = nm2 < big ? nm2 : big;
      m1 = nm1; m2 = nm2;
    }
    // lock-free global top-2 merge
    const u64 old = atomicMin(&min1g[row0 + tid], m1);
    u64 push = m1 < old ? old : m1;       // max(m1, old)
    push = m2 < push ? m2 : push;
    atomicMin(&min2g[row0 + tid], push);
  }
#undef GLOB_LOAD
#undef CONV_WRITE
}

// ---------------------------------------------------------------------------
// Flag rows whose approx top-2 margin < EPS; compact into worklist.
// Set of flagged rows is deterministic (order doesn't matter downstream).
// ---------------------------------------------------------------------------
__global__ __launch_bounds__(256) void vq_flag_kernel(
    const u64* __restrict__ min1g, const u64* __restrict__ min2g,
    int* __restrict__ count, int* __restrict__ list) {
  const int row = blockIdx.x * 256 + threadIdx.x;
  const float f1 = unfkey((uint32_t)(min1g[row] >> 32));
  const float f2 = unfkey((uint32_t)(min2g[row] >> 32));
  if (!(f2 - f1 >= EPS)) {              // also catches NaN
    const int p = atomicAdd(count, 1);
    list[p] = row;
  }
}

// ---------------------------------------------------------------------------
// Exact fp32 rescan of flagged rows. Fixed grid; work items = count*32,
// item = (row, 256-code chunk). Wave-cooperative dot: x row in registers
// (8 floats/lane), whole wave reads one contiguous 2KB embed row per code
// (coalesced — round-5 recheck was 64-way splintered), butterfly-reduce.
// ---------------------------------------------------------------------------
__global__ __launch_bounds__(256) void vq_exact_kernel(
    const float* __restrict__ x, const float* __restrict__ embed,
    const float* __restrict__ e2g, const int* __restrict__ count,
    const int* __restrict__ list, u64* __restrict__ min1g) {
  const int nItems = (*count) * 32;
  __shared__ u64 wbest[4];
  const int lane = threadIdx.x & 63;
  const int wv   = threadIdx.x >> 6;

  for (int it = blockIdx.x; it < nItems; it += RCB) {
    const int row   = list[it >> 5];
    const int cbase = (it & 31) * 256 + wv * 64;

    const float* xp = x + (size_t)row * D + lane * 8;
    const float4 xa = *(const float4*)xp;
    const float4 xb = *(const float4*)(xp + 4);

    float bv = 3.4e38f;
    int   bi = 0;
    for (int i = 0; i < 64; ++i) {
      const int c = cbase + i;
      const float* ep = embed + (size_t)c * D + lane * 8;
      const float4 ea = *(const float4*)ep;
      const float4 eb = *(const float4*)(ep + 4);
      float p = xa.x * ea.x + xa.y * ea.y + xa.z * ea.z + xa.w * ea.w +
                xb.x * eb.x + xb.y * eb.y + xb.z * eb.z + xb.w * eb.w;
#pragma unroll
      for (int m = 32; m >= 1; m >>= 1) p += __shfl_xor(p, m, 64);
      const float s = fmaf(-2.f, p, e2g[c]);
      if (s < bv) { bv = s; bi = c; }   // c ascending within wave
    }
    const u64 pk = ((u64)fkey(bv) << 32) | (uint32_t)bi;
    if (lane == 0) wbest[wv] = pk;
    __syncthreads();
    if (threadIdx.x == 0) {
      u64 m = wbest[0];
#pragma unroll
      for (int q = 1; q < 4; ++q) m = wbest[q] < m ? wbest[q] : m;
      atomicMin(&min1g[row], m);
    }
    __syncthreads();
  }
}

// ---------------------------------------------------------------------------
// Gather winning rows, write q, idx (as float), commit loss.
// ---------------------------------------------------------------------------
__global__ void vq_finish_kernel(const float* __restrict__ x,
                                 const float* __restrict__ embed,
                                 const u64* __restrict__ min1g,
                                 float* __restrict__ out_q,
                                 float* __restrict__ out_idx,
                                 float* __restrict__ out_loss) {
  const int row  = blockIdx.x * 4 + (threadIdx.x >> 6);
  const int lane = threadIdx.x & 63;
  const int idx  = (int)(min1g[row] & 0xFFFFFFFFull);
  if (lane == 0) out_idx[row] = (float)idx;

  const float* ep = embed + (size_t)idx * D + lane * 8;
  const float* xp = x + (size_t)row * D + lane * 8;
  float* qp       = out_q + (size_t)row * D + lane * 8;

  const float4 e0 = *(const float4*)ep;
  const float4 e1 = *(const float4*)(ep + 4);
  const float4 x0 = *(const float4*)xp;
  const float4 x1 = *(const float4*)(xp + 4);
  *(float4*)qp       = e0;   // x + sg(q - x) == q numerically
  *(float4*)(qp + 4) = e1;

  float l = (e0.x - x0.x) * (e0.x - x0.x) + (e0.y - x0.y) * (e0.y - x0.y) +
            (e0.z - x0.z) * (e0.z - x0.z) + (e0.w - x0.w) * (e0.w - x0.w) +
            (e1.x - x1.x) * (e1.x - x1.x) + (e1.y - x1.y) * (e1.y - x1.y) +
            (e1.z - x1.z) * (e1.z - x1.z) + (e1.w - x1.w) * (e1.w - x1.w);
#pragma unroll
  for (int m = 32; m >= 1; m >>= 1) l += __shfl_xor(l, m, 64);
  if (lane == 0)
    atomicAdd(out_loss, l * (1.f / (float)((size_t)NROWS * D)));
}

// ---------------------------------------------------------------------------
extern "C" void kernel_launch(void* const* d_in, const int* in_sizes, int n_in,
                              void* d_out, int out_size, void* d_ws,
                              size_t ws_size, hipStream_t stream) {
  (void)in_sizes; (void)n_in; (void)out_size; (void)ws_size;
  const float* x     = (const float*)d_in[0];
  const float* embed = (const float*)d_in[1];

  char* ws = (char*)d_ws;
  u64*  min1  = (u64*)ws;                                  // 16384 u64
  u64*  min2  = (u64*)(ws + (size_t)NROWS * 8);            // 16384 u64
  float* e2   = (float*)(ws + (size_t)NROWS * 16);         // 8192 f32
  int*  count = (int*)(ws + (size_t)NROWS * 16 + NCODES * 4);
  int*  list  = (int*)(ws + (size_t)NROWS * 16 + NCODES * 4 + 16);

  float* out_q    = (float*)d_out;                 // [16384][512]
  float* out_idx  = out_q + (size_t)NROWS * D;     // [16384] as float
  float* out_loss = out_idx + NROWS;               // [1]

  hipMemsetAsync(d_ws, 0xFF, (size_t)NROWS * 16, stream);  // min1+min2
  hipMemsetAsync(count, 0, sizeof(int), stream);
  hipMemsetAsync(out_loss, 0, sizeof(float), stream);
  vq_e2_kernel<<<NCODES / 4, 256, 0, stream>>>(embed, e2);
  vq_mfma_kernel<<<NBLK, 512, 0, stream>>>(x, embed, e2, min1, min2);
  vq_flag_kernel<<<NROWS / 256, 256, 0, stream>>>(min1, min2, count, list);
  vq_exact_kernel<<<RCB, 256, 0, stream>>>(x, embed, e2, count, list, min1);
  vq_finish_kernel<<<NROWS / 4, 256, 0, stream>>>(x, embed, min1, out_q,
                                                  out_idx, out_loss);
}

// Round 7
// 646.490 us; speedup vs baseline: 43.5165x; 1.1106x over previous
//
#include <hip/hip_runtime.h>
#include <cstdint>
#include <cstddef>

#define D       512
#define NROWS   16384
#define NCODES  8192
#define BM      128
#define BN      128
#define BK      32
#define NKC     (D / BK)        // 16
#define RB      (NROWS / BM)    // 128
#define CB      (NCODES / BN)   // 64
#define NBLK    (RB * CB)       // 8192
#define EPS     0.02f
#define RCB     1024
#define TILE_BYTES 16384        // per (blk,kc): [HI 8KB][LO 8KB]

typedef __attribute__((ext_vector_type(8))) short short8;  // 8 bf16
typedef __attribute__((ext_vector_type(4))) float f32x4;
typedef unsigned long long u64;
typedef __attribute__((address_space(3))) uint32_t as3_u32;
typedef __attribute__((address_space(1))) uint32_t as1_u32;

// order-preserving fp32 <-> u32 key
__device__ __forceinline__ uint32_t fkey(float f) {
  uint32_t u = __float_as_uint(f);
  return (u & 0x80000000u) ? ~u : (u | 0x80000000u);
}
__device__ __forceinline__ float unfkey(uint32_t k) {
  uint32_t u = (k & 0x80000000u) ? (k & 0x7FFFFFFFu) : ~k;
  return __uint_as_float(u);
}
// round-to-nearest bf16, returned as high-aligned fp32 bits
__device__ __forceinline__ uint32_t bfhi(float f) {
  uint32_t u = __float_as_uint(f);
  return (u + 0x7FFFu + ((u >> 16) & 1u)) & 0xFFFF0000u;
}

// ---------------------------------------------------------------------------
// Pre-pack: fp32 [nrows][512] -> bf16 hi/lo planes in tile-kc order.
// Chunk (8 bf16 = 16 B) for (row r in 128-block, k-quarter c) stored at
// physical chunk c ^ ((r>>1)&3)  -> conflict-free b128 frag reads in LDS.
// One thread per 16 B output chunk; each element converted exactly ONCE
// (round 6 converted embed tiles 64x and x tiles 32x inside the hot loop).
// ---------------------------------------------------------------------------
__global__ __launch_bounds__(256) void vq_pack_kernel(
    const float* __restrict__ src, uint32_t* __restrict__ dst) {
  const int t   = blockIdx.x * 256 + threadIdx.x;   // chunk id (grid exact)
  const int row = t >> 6;
  const int q   = t & 63;
  const int kc  = q >> 2, c = q & 3;
  const int blk = row >> 7, r = row & 127;
  const int cp  = c ^ ((r >> 1) & 3);

  const float* sp = src + (size_t)row * D + kc * 32 + c * 8;
  const float4 v0 = *(const float4*)sp;
  const float4 v1 = *(const float4*)(sp + 4);
  const float f[8] = {v0.x, v0.y, v0.z, v0.w, v1.x, v1.y, v1.z, v1.w};
  uint32_t hi[4], lo[4];
#pragma unroll
  for (int p = 0; p < 4; ++p) {
    const uint32_t h0 = bfhi(f[2 * p]), h1 = bfhi(f[2 * p + 1]);
    hi[p] = (h0 >> 16) | (h1 & 0xFFFF0000u);
    const float l0 = f[2 * p] - __uint_as_float(h0);
    const float l1 = f[2 * p + 1] - __uint_as_float(h1);
    lo[p] = (bfhi(l0) >> 16) | (bfhi(l1) & 0xFFFF0000u);
  }
  uint32_t* dp = dst + (size_t)(blk * NKC + kc) * (TILE_BYTES / 4) + r * 16 + cp * 4;
  *(uint4*)dp          = make_uint4(hi[0], hi[1], hi[2], hi[3]);   // HI plane
  *(uint4*)(dp + 2048) = make_uint4(lo[0], lo[1], lo[2], lo[3]);   // LO plane
}

// ---------------------------------------------------------------------------
__global__ void vq_e2_kernel(const float* __restrict__ embed,
                             float* __restrict__ e2) {
  const int w    = (blockIdx.x * blockDim.x + threadIdx.x) >> 6;
  const int lane = threadIdx.x & 63;
  const float* p = embed + (size_t)w * D + lane * 8;
  const float4 a = *(const float4*)p;
  const float4 b = *(const float4*)(p + 4);
  float s = a.x * a.x + a.y * a.y + a.z * a.z + a.w * a.w +
            b.x * b.x + b.y * b.y + b.z * b.z + b.w * b.w;
#pragma unroll
  for (int m = 32; m >= 1; m >>= 1) s += __shfl_xor(s, m, 64);
  if (lane == 0) e2[w] = s;
}

// ---------------------------------------------------------------------------
// MFMA distance kernel on pre-packed bf16 planes.
// 128x128 tile, 4 waves (wave tile 64x64), BK=32, 32 KB LDS -> 3-4 blocks/CU.
// Staging = pure global_load_lds dwordx4 (no VALU conversion, no VGPR trip).
// 3-term split GEMM: hh + hl + lh. Exact global top-2 via atomicMin protocol.
// ---------------------------------------------------------------------------
__global__ __launch_bounds__(256) void vq_mfma_kernel(
    const uint32_t* __restrict__ xp, const uint32_t* __restrict__ ep,
    const float* __restrict__ e2g,
    u64* __restrict__ min1g, u64* __restrict__ min2g) {
  __shared__ __align__(16) char smem[32768];
  // [0,8K) XH | [8K,16K) XL | [16K,24K) EH | [24K,32K) EL

  const int tid  = threadIdx.x;
  const int lane = tid & 63;
  const int w    = tid >> 6;          // 0..3
  const int wr   = (w >> 1) * 64;
  const int wcI  = w & 1;
  const int wc   = wcI * 64;

  // XCD swizzle: 8 cb per XCD (2 MB packed embed slice fits 4 MB L2);
  // cb fast-varying within rb -> x tile L2-reuse across 8 cbs.
  const int xcd = blockIdx.x & 7;
  const int id  = blockIdx.x >> 3;     // 0..1023
  const int cb  = xcd * 8 + (id & 7);  // 0..63
  const int rb  = id >> 3;             // 0..127
  const int row0 = rb * BM;
  const int c0   = cb * BN;

  const char* xtile = (const char*)xp + (size_t)rb * NKC * TILE_BYTES;
  const char* etile = (const char*)ep + (size_t)cb * NKC * TILE_BYTES;

  f32x4 acc[4][4];
#pragma unroll
  for (int i = 0; i < 4; ++i)
#pragma unroll
    for (int j = 0; j < 4; ++j) acc[i][j] = (f32x4)0.f;

  const int fr = lane & 15;
  const int cl = lane >> 4;
  const int cs = (cl ^ ((fr >> 1) & 3)) * 16;  // swizzled k-quarter byte off

  for (int kc = 0; kc < NKC; ++kc) {
    if (kc) __syncthreads();           // prev tile fully consumed
    {
      const char* gx = xtile + kc * TILE_BYTES + tid * 16;
      const char* ge = etile + kc * TILE_BYTES + tid * 16;
#pragma unroll
      for (int s = 0; s < 4; ++s) {
        __builtin_amdgcn_global_load_lds(
            (const as1_u32*)(const void*)(gx + s * 4096),
            (as3_u32*)(void*)(smem + tid * 16 + s * 4096), 16, 0, 0);
        __builtin_amdgcn_global_load_lds(
            (const as1_u32*)(const void*)(ge + s * 4096),
            (as3_u32*)(void*)(smem + 16384 + tid * 16 + s * 4096), 16, 0, 0);
      }
    }
    __syncthreads();                   // drains vmcnt(0): tile visible

    short8 bh[4], bl[4];
#pragma unroll
    for (int j = 0; j < 4; ++j) {
      const int rbrow = wc + j * 16 + fr;
      bh[j] = *(const short8*)(smem + 16384 + rbrow * 64 + cs);
      bl[j] = *(const short8*)(smem + 24576 + rbrow * 64 + cs);
    }
#pragma unroll
    for (int i = 0; i < 4; ++i) {
      const int arow = wr + i * 16 + fr;
      const short8 ah = *(const short8*)(smem + arow * 64 + cs);
      const short8 al = *(const short8*)(smem + 8192 + arow * 64 + cs);
#pragma unroll
      for (int j = 0; j < 4; ++j) {
        acc[i][j] = __builtin_amdgcn_mfma_f32_16x16x32_bf16(ah, bh[j], acc[i][j], 0, 0, 0);
        acc[i][j] = __builtin_amdgcn_mfma_f32_16x16x32_bf16(ah, bl[j], acc[i][j], 0, 0, 0);
        acc[i][j] = __builtin_amdgcn_mfma_f32_16x16x32_bf16(al, bh[j], acc[i][j], 0, 0, 0);
      }
    }
  }

  // ---- epilogue: per-row top-2 over this block's 128 codes ----
  float e2v[4];
#pragma unroll
  for (int j = 0; j < 4; ++j) e2v[j] = e2g[c0 + wc + j * 16 + fr];

  __syncthreads();                     // MFMA LDS reads done; reuse smem
  u64 (*mb)[2][2] = (u64(*)[2][2])smem;  // [128 rows][wcIdx][min1,min2]

#pragma unroll
  for (int i = 0; i < 4; ++i) {
#pragma unroll
    for (int r = 0; r < 4; ++r) {
      float v1 = 3.4e38f, v2 = 3.4e38f;
      int c1 = 0;
#pragma unroll
      for (int j = 0; j < 4; ++j) {
        const float s = fmaf(-2.f, acc[i][j][r], e2v[j]);
        if (s < v1) { v2 = v1; v1 = s; c1 = c0 + wc + j * 16 + fr; }
        else if (s < v2) v2 = s;
      }
      u64 p1 = ((u64)fkey(v1) << 32) | (uint32_t)c1;
      uint32_t k2 = fkey(v2);
#pragma unroll
      for (int m = 8; m >= 1; m >>= 1) {   // merge across 16-lane row-group
        const u64 o1 = __shfl_xor(p1, m, 64);
        const uint32_t o2 = __shfl_xor(k2, m, 64);
        const u64 lo_ = p1 < o1 ? p1 : o1;
        const u64 hi_ = p1 < o1 ? o1 : p1;
        uint32_t nk = k2 < o2 ? k2 : o2;
        const uint32_t hk = (uint32_t)(hi_ >> 32);
        k2 = nk < hk ? nk : hk;
        p1 = lo_;
      }
      if ((lane & 15) == 0) {
        const int lrow = wr + i * 16 + (lane >> 4) * 4 + r;
        mb[lrow][wcI][0] = p1;
        mb[lrow][wcI][1] = ((u64)k2 << 32) | 0xFFFFFFFFull;
      }
    }
  }
  __syncthreads();

  if (tid < BM) {
    u64 m1 = mb[tid][0][0], m2 = mb[tid][0][1];
    const u64 a1 = mb[tid][1][0], a2 = mb[tid][1][1];
    const u64 nm1 = m1 < a1 ? m1 : a1;
    const u64 big = m1 < a1 ? a1 : m1;
    u64 nm2 = m2 < a2 ? m2 : a2;
    nm2 = nm2 < big ? nm2 : big;
    // lock-free global top-2 merge
    const u64 old = atomicMin(&min1g[row0 + tid], nm1);
    u64 push = nm1 < old ? old : nm1;       // max(m1, old)
    push = nm2 < push ? nm2 : push;
    atomicMin(&min2g[row0 + tid], push);
  }
}

// ---------------------------------------------------------------------------
__global__ __launch_bounds__(256) void vq_flag_kernel(
    const u64* __restrict__ min1g, const u64* __restrict__ min2g,
    int* __restrict__ count, int* __restrict__ list) {
  const int row = blockIdx.x * 256 + threadIdx.x;
  const float f1 = unfkey((uint32_t)(min1g[row] >> 32));
  const float f2 = unfkey((uint32_t)(min2g[row] >> 32));
  if (!(f2 - f1 >= EPS)) {              // also catches NaN
    const int p = atomicAdd(count, 1);
    list[p] = row;
  }
}

// ---------------------------------------------------------------------------
__global__ __launch_bounds__(256) void vq_exact_kernel(
    const float* __restrict__ x, const float* __restrict__ embed,
    const float* __restrict__ e2g, const int* __restrict__ count,
    const int* __restrict__ list, u64* __restrict__ min1g) {
  const int nItems = (*count) * 32;
  __shared__ u64 wbest[4];
  const int lane = threadIdx.x & 63;
  const int wv   = threadIdx.x >> 6;

  for (int it = blockIdx.x; it < nItems; it += RCB) {
    const int row   = list[it >> 5];
    const int cbase = (it & 31) * 256 + wv * 64;

    const float* xp = x + (size_t)row * D + lane * 8;
    const float4 xa = *(const float4*)xp;
    const float4 xb = *(const float4*)(xp + 4);

    float bv = 3.4e38f;
    int   bi = 0;
    for (int i = 0; i < 64; ++i) {
      const int c = cbase + i;
      const float* epr = embed + (size_t)c * D + lane * 8;
      const float4 ea = *(const float4*)epr;
      const float4 eb = *(const float4*)(epr + 4);
      float p = xa.x * ea.x + xa.y * ea.y + xa.z * ea.z + xa.w * ea.w +
                xb.x * eb.x + xb.y * eb.y + xb.z * eb.z + xb.w * eb.w;
#pragma unroll
      for (int m = 32; m >= 1; m >>= 1) p += __shfl_xor(p, m, 64);
      const float s = fmaf(-2.f, p, e2g[c]);
      if (s < bv) { bv = s; bi = c; }
    }
    const u64 pk = ((u64)fkey(bv) << 32) | (uint32_t)bi;
    if (lane == 0) wbest[wv] = pk;
    __syncthreads();
    if (threadIdx.x == 0) {
      u64 m = wbest[0];
#pragma unroll
      for (int q = 1; q < 4; ++q) m = wbest[q] < m ? wbest[q] : m;
      atomicMin(&min1g[row], m);
    }
    __syncthreads();
  }
}

// ---------------------------------------------------------------------------
__global__ void vq_finish_kernel(const float* __restrict__ x,
                                 const float* __restrict__ embed,
                                 const u64* __restrict__ min1g,
                                 float* __restrict__ out_q,
                                 float* __restrict__ out_idx,
                                 float* __restrict__ out_loss) {
  const int row  = blockIdx.x * 4 + (threadIdx.x >> 6);
  const int lane = threadIdx.x & 63;
  const int idx  = (int)(min1g[row] & 0xFFFFFFFFull);
  if (lane == 0) out_idx[row] = (float)idx;

  const float* ep = embed + (size_t)idx * D + lane * 8;
  const float* xp = x + (size_t)row * D + lane * 8;
  float* qp       = out_q + (size_t)row * D + lane * 8;

  const float4 e0 = *(const float4*)ep;
  const float4 e1 = *(const float4*)(ep + 4);
  const float4 x0 = *(const float4*)xp;
  const float4 x1 = *(const float4*)(xp + 4);
  *(float4*)qp       = e0;   // x + sg(q - x) == q numerically
  *(float4*)(qp + 4) = e1;

  float l = (e0.x - x0.x) * (e0.x - x0.x) + (e0.y - x0.y) * (e0.y - x0.y) +
            (e0.z - x0.z) * (e0.z - x0.z) + (e0.w - x0.w) * (e0.w - x0.w) +
            (e1.x - x1.x) * (e1.x - x1.x) + (e1.y - x1.y) * (e1.y - x1.y) +
            (e1.z - x1.z) * (e1.z - x1.z) + (e1.w - x1.w) * (e1.w - x1.w);
#pragma unroll
  for (int m = 32; m >= 1; m >>= 1) l += __shfl_xor(l, m, 64);
  if (lane == 0)
    atomicAdd(out_loss, l * (1.f / (float)((size_t)NROWS * D)));
}

// ---------------------------------------------------------------------------
extern "C" void kernel_launch(void* const* d_in, const int* in_sizes, int n_in,
                              void* d_out, int out_size, void* d_ws,
                              size_t ws_size, hipStream_t stream) {
  (void)in_sizes; (void)n_in; (void)out_size; (void)ws_size;
  const float* x     = (const float*)d_in[0];
  const float* embed = (const float*)d_in[1];

  char* ws = (char*)d_ws;
  u64*  min1  = (u64*)ws;                                  // 128 KB
  u64*  min2  = (u64*)(ws + (size_t)NROWS * 8);            // 128 KB
  float* e2   = (float*)(ws + (size_t)NROWS * 16);         // 32 KB
  int*  count = (int*)(ws + (size_t)NROWS * 16 + NCODES * 4);
  int*  list  = (int*)(ws + (size_t)NROWS * 16 + NCODES * 4 + 16);
  // packed bf16 hi/lo planes (needs ws >= ~50 MB)
  uint32_t* pack_x = (uint32_t*)(ws + (1u << 19));                  // 32 MB
  uint32_t* pack_e = (uint32_t*)(ws + (1u << 19) + ((size_t)RB * NKC * TILE_BYTES));

  float* out_q    = (float*)d_out;                 // [16384][512]
  float* out_idx  = out_q + (size_t)NROWS * D;     // [16384] as float
  float* out_loss = out_idx + NROWS;               // [1]

  hipMemsetAsync(d_ws, 0xFF, (size_t)NROWS * 16, stream);  // min1+min2
  hipMemsetAsync(count, 0, sizeof(int), stream);
  hipMemsetAsync(out_loss, 0, sizeof(float), stream);
  vq_pack_kernel<<<NROWS * 64 / 256, 256, 0, stream>>>(x, pack_x);
  vq_pack_kernel<<<NCODES * 64 / 256, 256, 0, stream>>>(embed, pack_e);
  vq_e2_kernel<<<NCODES / 4, 256, 0, stream>>>(embed, e2);
  vq_mfma_kernel<<<NBLK, 256, 0, stream>>>(pack_x, pack_e, e2, min1, min2);
  vq_flag_kernel<<<NROWS / 256, 256, 0, stream>>>(min1, min2, count, list);
  vq_exact_kernel<<<RCB, 256, 0, stream>>>(x, embed, e2, count, list, min1);
  vq_finish_kernel<<<NROWS / 4, 256, 0, stream>>>(x, embed, min1, out_q,
                                                  out_idx, out_loss);
}